// Round 10
// baseline (45.064 us; speedup 1.0000x reference)
//
#include <hip/hip_runtime.h>

#define FIN   1024
#define FOUT2 1024
#define NTASK 20
#define NRG   128                 // row-groups of 8 output rows
#define NSLOT 2                   // sample slots (round-7/9 proven value)
#define NW    (NTASK * NRG * NSLOT)   // 5120 single-wave blocks
#define HOFF  (256 * 512)         // h output elements before logits

// Round-10: round-9 barrier-free single-wave skeleton with 8 rows/wave.
//  - Halves x L2 traffic (256 MB -> 128 MB) and wave count (10240 -> 5120);
//    doubles per-iteration ILP (16 independent FMA chains).
//  - wr[8][4] = 128 pinned VGPRs; ~220 total -> 2 waves/SIMD.
//  - Reduction tree gains one fold level (bit4); still bit-identical to the
//    full 64-lane butterfly (XOR stages 32,16,8,4,2,1; folds select the
//    bitwise-identical surviving value).
// Sample ordering, slot split, per-dot FMA order unchanged from round 9.
__global__ __launch_bounds__(64, 2)
void cond_linear_kernel(const float* __restrict__ x,
                        const int* __restrict__ task_id,
                        const float* __restrict__ W,
                        float* __restrict__ out) {
    __shared__ int sh_ord[64];

    const int lane = threadIdx.x;          // block == one wave
    const int bid  = blockIdx.x;
    const int orig = (bid & 7) * (NW / 8) + (bid >> 3);   // XCD-chunk swizzle
    const int t    = orig >> 8;            // 256 blocks per task
    const int r2   = orig & 255;
    const int rg   = r2 >> 1;              // row-group (8 rows)
    const int slot = r2 & 1;
    const int o0   = rg * 8;               // this wave's 8 output rows

    // ---- issue the 32 W loads FIRST (no barrier anywhere -> no drain) ----
    const float* Wt = W + (size_t)t * (FOUT2 * FIN);
    float4 wr[8][4];
    #pragma unroll
    for (int r = 0; r < 8; ++r) {
        const float4* wp = (const float4*)(Wt + (size_t)(o0 + r) * FIN);
        #pragma unroll
        for (int p = 0; p < 4; ++p)
            wr[r][p] = wp[p * 64 + lane];
    }

    // ---- barrier-free sample list: ballot + rank + per-wave LDS scatter ----
    const int4 ids = ((const int4*)task_id)[lane];        // samples 4l..4l+3
    const unsigned long long m0 = __ballot(ids.x == t);
    const unsigned long long m1 = __ballot(ids.y == t);
    const unsigned long long m2 = __ballot(ids.z == t);
    const unsigned long long m3 = __ballot(ids.w == t);
    const unsigned long long below = (1ull << lane) - 1ull;
    int rank = __popcll(m0 & below) + __popcll(m1 & below)
             + __popcll(m2 & below) + __popcll(m3 & below);
    if (ids.x == t) sh_ord[rank] = 4 * lane + 0;
    rank += (int)((m0 >> lane) & 1);
    if (ids.y == t) sh_ord[rank] = 4 * lane + 1;
    rank += (int)((m1 >> lane) & 1);
    if (ids.z == t) sh_ord[rank] = 4 * lane + 2;
    rank += (int)((m2 >> lane) & 1);
    if (ids.w == t) sh_ord[rank] = 4 * lane + 3;

    const int n = __popcll(m0) + __popcll(m1) + __popcll(m2) + __popcll(m3);
    const int half = (n + 1) >> 1;
    const int i0 = slot ? half : 0;
    const int i1 = slot ? n    : half;
    if (i0 >= i1) return;

    // ---- PIN W in VGPRs (no remat possible) ----
    #pragma unroll
    for (int r = 0; r < 8; ++r)
        #pragma unroll
        for (int p = 0; p < 4; ++p)
            asm volatile("" : "+v"(wr[r][p].x), "+v"(wr[r][p].y),
                              "+v"(wr[r][p].z), "+v"(wr[r][p].w));

    // lane identity bits for the folded tree
    const bool hi32 = (lane & 32) != 0;
    const bool hi16 = (lane & 16) != 0;
    const bool hi8  = (lane & 8)  != 0;
    const bool hi4  = (lane & 4)  != 0;

    // ---- preload first sample pair ----
    int sa = sh_ord[i0];
    int sb = sh_ord[(i0 + 1 < i1) ? i0 + 1 : i1 - 1];
    float4 xa[4], xb[4];
    #pragma unroll
    for (int p = 0; p < 4; ++p)
        xa[p] = ((const float4*)(x + (size_t)sa * FIN))[p * 64 + lane];
    #pragma unroll
    for (int p = 0; p < 4; ++p)
        xb[p] = ((const float4*)(x + (size_t)sb * FIN))[p * 64 + lane];

    for (int i = i0; i < i1; i += 2) {
        // prefetch next pair (clamped; tail duplicates are benign)
        const int ina = (i + 2 < i1) ? i + 2 : i1 - 1;
        const int inb = (i + 3 < i1) ? i + 3 : i1 - 1;
        const int na_s = sh_ord[ina];
        const int nb_s = sh_ord[inb];
        float4 na[4], nb[4];
        #pragma unroll
        for (int p = 0; p < 4; ++p)
            na[p] = ((const float4*)(x + (size_t)na_s * FIN))[p * 64 + lane];
        #pragma unroll
        for (int p = 0; p < 4; ++p)
            nb[p] = ((const float4*)(x + (size_t)nb_s * FIN))[p * 64 + lane];

        float aacc[8], bacc[8];
        #pragma unroll
        for (int r = 0; r < 8; ++r) { aacc[r] = 0.f; bacc[r] = 0.f; }

        #pragma unroll
        for (int p = 0; p < 4; ++p) {
            const float4 u = xa[p];
            const float4 v = xb[p];
            #pragma unroll
            for (int r = 0; r < 8; ++r) {
                aacc[r] += wr[r][p].x * u.x + wr[r][p].y * u.y
                         + wr[r][p].z * u.z + wr[r][p].w * u.w;
                bacc[r] += wr[r][p].x * v.x + wr[r][p].y * v.y
                         + wr[r][p].z * v.z + wr[r][p].w * v.w;
            }
        }

        // ---- folded reduction tree (bit-identical to full 32..1 butterfly) ----
        // stage 32 on all 16 values
        float t_[16];
        #pragma unroll
        for (int r = 0; r < 8; ++r) {
            t_[r]     = aacc[r] + __shfl_xor(aacc[r], 32, 64);
            t_[8 + r] = bacc[r] + __shfl_xor(bacc[r], 32, 64);
        }
        // fold by bit32 (sample), then stage 16
        float w_[8];
        #pragma unroll
        for (int r = 0; r < 8; ++r) w_[r] = hi32 ? t_[8 + r] : t_[r];
        #pragma unroll
        for (int r = 0; r < 8; ++r) w_[r] += __shfl_xor(w_[r], 16, 64);
        // fold by bit16 (row bit2), then stage 8
        float u_[4];
        #pragma unroll
        for (int j = 0; j < 4; ++j) u_[j] = hi16 ? w_[j + 4] : w_[j];
        #pragma unroll
        for (int j = 0; j < 4; ++j) u_[j] += __shfl_xor(u_[j], 8, 64);
        // fold by bit8 (row bit1), then stage 4
        float v_[2];
        #pragma unroll
        for (int j = 0; j < 2; ++j) v_[j] = hi8 ? u_[j + 2] : u_[j];
        #pragma unroll
        for (int j = 0; j < 2; ++j) v_[j] += __shfl_xor(v_[j], 4, 64);
        // fold by bit4 (row bit0), then stages 2,1
        float z = hi4 ? v_[1] : v_[0];
        z += __shfl_xor(z, 2, 64);
        z += __shfl_xor(z, 1, 64);
        const float zp = __shfl_xor(z, 4, 64);   // partner row (r^1)

        const int r_id  = (hi4 ? 1 : 0) + (hi8 ? 2 : 0) + (hi16 ? 4 : 0);
        const int s_idx = hi32 ? sb : sa;
        if ((lane & 3) == 0) {
            out[HOFF + (size_t)s_idx * FOUT2 + o0 + r_id] = z;
            if (!hi4) {   // even row: h = (logit_even >= logit_odd)
                out[(size_t)s_idx * (FOUT2 / 2) + (o0 >> 1)
                    + (hi16 ? 2 : 0) + (hi8 ? 1 : 0)]
                    = (z >= zp) ? 1.0f : 0.0f;
            }
        }

        sa = na_s; sb = nb_s;
        #pragma unroll
        for (int p = 0; p < 4; ++p) { xa[p] = na[p]; xb[p] = nb[p]; }
    }
}

extern "C" void kernel_launch(void* const* d_in, const int* in_sizes, int n_in,
                              void* d_out, int out_size, void* d_ws, size_t ws_size,
                              hipStream_t stream) {
    const float* x       = (const float*)d_in[0];
    const int*   task_id = (const int*)d_in[1];
    const float* W       = (const float*)d_in[2];
    float*       out     = (float*)d_out;

    dim3 grid(NW);
    dim3 block(64);
    hipLaunchKernelGGL(cond_linear_kernel, grid, block, 0, stream,
                       x, task_id, W, out);
}

// Round 11
// 41.655 us; speedup vs baseline: 1.0818x; 1.0818x over previous
//
#include <hip/hip_runtime.h>

#define FIN   1024
#define FOUT2 1024
#define NTASK 20
#define NRG   128                 // row-groups of 8 output rows
#define NSLOT 2                   // sample slots
#define NW    (NTASK * NRG * NSLOT)   // 5120 single-wave blocks
#define HOFF  (256 * 512)         // h output elements before logits

// Round-11: 8 rows/wave done right.
//  - amdgpu_waves_per_eu(2,2): min=max=2 -> full 256-VGPR budget, no
//    occupancy-driven spilling (round 10's failure: VGPR=100 + LDS spill).
//  - single-sample iterations + 1-deep prefetch: working set ~200 VGPRs.
//  - barrier-free single-wave blocks, ballot/rank list, pinned W, XCD swizzle
//    as in round 9. Per-dot FMA order and fold-tree equivalence unchanged.
__global__
__attribute__((amdgpu_flat_work_group_size(64, 64), amdgpu_waves_per_eu(2, 2)))
void cond_linear_kernel(const float* __restrict__ x,
                        const int* __restrict__ task_id,
                        const float* __restrict__ W,
                        float* __restrict__ out) {
    __shared__ int sh_ord[64];

    const int lane = threadIdx.x;          // block == one wave
    const int bid  = blockIdx.x;
    const int orig = (bid & 7) * (NW / 8) + (bid >> 3);   // XCD-chunk swizzle
    const int t    = orig >> 8;            // 256 blocks per task
    const int r2   = orig & 255;
    const int rg   = r2 >> 1;              // row-group (8 rows)
    const int slot = r2 & 1;
    const int o0   = rg * 8;               // this wave's 8 output rows

    // ---- issue the 32 W loads FIRST (no barrier anywhere -> no drain) ----
    const float* Wt = W + (size_t)t * (FOUT2 * FIN);
    float4 wr[8][4];
    #pragma unroll
    for (int r = 0; r < 8; ++r) {
        const float4* wp = (const float4*)(Wt + (size_t)(o0 + r) * FIN);
        #pragma unroll
        for (int p = 0; p < 4; ++p)
            wr[r][p] = wp[p * 64 + lane];
    }

    // ---- barrier-free sample list: ballot + rank + per-wave LDS scatter ----
    const int4 ids = ((const int4*)task_id)[lane];        // samples 4l..4l+3
    const unsigned long long m0 = __ballot(ids.x == t);
    const unsigned long long m1 = __ballot(ids.y == t);
    const unsigned long long m2 = __ballot(ids.z == t);
    const unsigned long long m3 = __ballot(ids.w == t);
    const unsigned long long below = (1ull << lane) - 1ull;
    int rank = __popcll(m0 & below) + __popcll(m1 & below)
             + __popcll(m2 & below) + __popcll(m3 & below);
    if (ids.x == t) sh_ord[rank] = 4 * lane + 0;
    rank += (int)((m0 >> lane) & 1);
    if (ids.y == t) sh_ord[rank] = 4 * lane + 1;
    rank += (int)((m1 >> lane) & 1);
    if (ids.z == t) sh_ord[rank] = 4 * lane + 2;
    rank += (int)((m2 >> lane) & 1);
    if (ids.w == t) sh_ord[rank] = 4 * lane + 3;

    const int n = __popcll(m0) + __popcll(m1) + __popcll(m2) + __popcll(m3);
    const int half = (n + 1) >> 1;
    const int i0 = slot ? half : 0;
    const int i1 = slot ? n    : half;
    if (i0 >= i1) return;

    // ---- PIN W in VGPRs (no remat possible) ----
    #pragma unroll
    for (int r = 0; r < 8; ++r)
        #pragma unroll
        for (int p = 0; p < 4; ++p)
            asm volatile("" : "+v"(wr[r][p].x), "+v"(wr[r][p].y),
                              "+v"(wr[r][p].z), "+v"(wr[r][p].w));

    // lane identity bits for the folded tree (row = hi8,hi16,hi32 bits)
    const bool hi32 = (lane & 32) != 0;
    const bool hi16 = (lane & 16) != 0;
    const bool hi8  = (lane & 8)  != 0;

    // ---- preload first sample ----
    int sa = sh_ord[i0];
    float4 xa[4];
    #pragma unroll
    for (int p = 0; p < 4; ++p)
        xa[p] = ((const float4*)(x + (size_t)sa * FIN))[p * 64 + lane];

    for (int i = i0; i < i1; ++i) {
        // prefetch next sample (clamped; tail duplicate is benign)
        const int inx = (i + 1 < i1) ? i + 1 : i1 - 1;
        const int ns  = sh_ord[inx];
        float4 nx[4];
        #pragma unroll
        for (int p = 0; p < 4; ++p)
            nx[p] = ((const float4*)(x + (size_t)ns * FIN))[p * 64 + lane];

        float acc[8];
        #pragma unroll
        for (int r = 0; r < 8; ++r) acc[r] = 0.f;

        #pragma unroll
        for (int p = 0; p < 4; ++p) {
            const float4 u = xa[p];
            #pragma unroll
            for (int r = 0; r < 8; ++r) {
                acc[r] += wr[r][p].x * u.x + wr[r][p].y * u.y
                        + wr[r][p].z * u.z + wr[r][p].w * u.w;
            }
        }

        // ---- folded reduction tree (bit-identical to full 32..1 butterfly) ----
        // stage 32 on all 8 row values
        float t_[8];
        #pragma unroll
        for (int r = 0; r < 8; ++r) t_[r] = acc[r] + __shfl_xor(acc[r], 32, 64);
        // fold by bit32 (row bit2), then stage 16
        float w_[4];
        #pragma unroll
        for (int j = 0; j < 4; ++j) w_[j] = hi32 ? t_[j + 4] : t_[j];
        #pragma unroll
        for (int j = 0; j < 4; ++j) w_[j] += __shfl_xor(w_[j], 16, 64);
        // fold by bit16 (row bit1), then stage 8
        float u_[2];
        #pragma unroll
        for (int j = 0; j < 2; ++j) u_[j] = hi16 ? w_[j + 2] : w_[j];
        #pragma unroll
        for (int j = 0; j < 2; ++j) u_[j] += __shfl_xor(u_[j], 8, 64);
        // fold by bit8 (row bit0), then stages 4,2,1
        float z = hi8 ? u_[1] : u_[0];
        z += __shfl_xor(z, 4, 64);
        z += __shfl_xor(z, 2, 64);
        z += __shfl_xor(z, 1, 64);
        const float zp = __shfl_xor(z, 8, 64);   // partner row (r^1)

        const int r_id = (hi8 ? 1 : 0) + (hi16 ? 2 : 0) + (hi32 ? 4 : 0);
        if ((lane & 7) == 0) {
            out[HOFF + (size_t)sa * FOUT2 + o0 + r_id] = z;
            if (!hi8) {   // even row: h = (logit_even >= logit_odd)
                out[(size_t)sa * (FOUT2 / 2) + (o0 >> 1)
                    + (hi16 ? 1 : 0) + (hi32 ? 2 : 0)]
                    = (z >= zp) ? 1.0f : 0.0f;
            }
        }

        sa = ns;
        #pragma unroll
        for (int p = 0; p < 4; ++p) xa[p] = nx[p];
    }
}

extern "C" void kernel_launch(void* const* d_in, const int* in_sizes, int n_in,
                              void* d_out, int out_size, void* d_ws, size_t ws_size,
                              hipStream_t stream) {
    const float* x       = (const float*)d_in[0];
    const int*   task_id = (const int*)d_in[1];
    const float* W       = (const float*)d_in[2];
    float*       out     = (float*)d_out;

    dim3 grid(NW);
    dim3 block(64);
    hipLaunchKernelGGL(cond_linear_kernel, grid, block, 0, stream,
                       x, task_id, W, out);
}

// Round 12
// 34.029 us; speedup vs baseline: 1.3243x; 1.2241x over previous
//
#include <hip/hip_runtime.h>

#define FIN   1024
#define FOUT2 1024
#define NTASK 20
#define NRG   256                 // row-groups of 4 output rows
#define NSLOT 2                   // sample slots (proven value)
#define NW    (NTASK * NRG * NSLOT)   // 10240 single-wave blocks
#define HOFF  (256 * 512)         // h output elements before logits

// Round-12 = round-9 (best, 29.4us) with ONE change: no software prefetch.
// Working set drops ~150 -> ~124 VGPRs; amdgpu_waves_per_eu(4,4) pins 4
// resident waves/SIMD (vs 2). x-load latency is hidden by TLP instead of ILP.
// Ballot/rank list, pinned W, fold tree, XCD swizzle, slot split: identical
// to round 9 -> bit-identical numerics.
__global__
__attribute__((amdgpu_flat_work_group_size(64, 64), amdgpu_waves_per_eu(4, 4)))
void cond_linear_kernel(const float* __restrict__ x,
                        const int* __restrict__ task_id,
                        const float* __restrict__ W,
                        float* __restrict__ out) {
    __shared__ int sh_ord[64];

    const int lane = threadIdx.x;          // block == one wave
    const int bid  = blockIdx.x;
    const int orig = (bid & 7) * (NW / 8) + (bid >> 3);   // XCD-chunk swizzle
    const int t    = orig >> 9;            // 512 blocks per task
    const int r2   = orig & 511;
    const int rg   = r2 >> 1;              // row-group (4 rows)
    const int slot = r2 & 1;
    const int o0   = rg * 4;               // this wave's 4 output rows

    // ---- issue the 16 W loads FIRST (no barrier anywhere -> no drain) ----
    const float* Wt = W + (size_t)t * (FOUT2 * FIN);
    float4 wr[4][4];
    #pragma unroll
    for (int r = 0; r < 4; ++r) {
        const float4* wp = (const float4*)(Wt + (size_t)(o0 + r) * FIN);
        #pragma unroll
        for (int p = 0; p < 4; ++p)
            wr[r][p] = wp[p * 64 + lane];
    }

    // ---- barrier-free sample list: ballot + rank + per-wave LDS scatter ----
    const int4 ids = ((const int4*)task_id)[lane];        // samples 4l..4l+3
    const unsigned long long m0 = __ballot(ids.x == t);
    const unsigned long long m1 = __ballot(ids.y == t);
    const unsigned long long m2 = __ballot(ids.z == t);
    const unsigned long long m3 = __ballot(ids.w == t);
    const unsigned long long below = (1ull << lane) - 1ull;
    int rank = __popcll(m0 & below) + __popcll(m1 & below)
             + __popcll(m2 & below) + __popcll(m3 & below);
    if (ids.x == t) sh_ord[rank] = 4 * lane + 0;
    rank += (int)((m0 >> lane) & 1);
    if (ids.y == t) sh_ord[rank] = 4 * lane + 1;
    rank += (int)((m1 >> lane) & 1);
    if (ids.z == t) sh_ord[rank] = 4 * lane + 2;
    rank += (int)((m2 >> lane) & 1);
    if (ids.w == t) sh_ord[rank] = 4 * lane + 3;

    const int n = __popcll(m0) + __popcll(m1) + __popcll(m2) + __popcll(m3);
    const int half = (n + 1) >> 1;
    const int i0 = slot ? half : 0;
    const int i1 = slot ? n    : half;
    if (i0 >= i1) return;

    // ---- PIN W in VGPRs (no remat possible) ----
    #pragma unroll
    for (int r = 0; r < 4; ++r)
        #pragma unroll
        for (int p = 0; p < 4; ++p)
            asm volatile("" : "+v"(wr[r][p].x), "+v"(wr[r][p].y),
                              "+v"(wr[r][p].z), "+v"(wr[r][p].w));

    // lane identity bits for the folded tree
    const bool hi32 = (lane & 32) != 0;
    const bool hi16 = (lane & 16) != 0;
    const bool hi8  = (lane & 8)  != 0;

    for (int i = i0; i < i1; i += 2) {
        const int sa = sh_ord[i];
        const int sb = sh_ord[(i + 1 < i1) ? i + 1 : i1 - 1];

        // load the pair's x rows (no prefetch buffers -> fits 128-VGPR budget)
        float4 xa[4], xb[4];
        #pragma unroll
        for (int p = 0; p < 4; ++p)
            xa[p] = ((const float4*)(x + (size_t)sa * FIN))[p * 64 + lane];
        #pragma unroll
        for (int p = 0; p < 4; ++p)
            xb[p] = ((const float4*)(x + (size_t)sb * FIN))[p * 64 + lane];

        float a0 = 0.f, a1 = 0.f, a2 = 0.f, a3 = 0.f;
        float b0 = 0.f, b1 = 0.f, b2 = 0.f, b3 = 0.f;
        #pragma unroll
        for (int p = 0; p < 4; ++p) {
            const float4 u = xa[p];
            const float4 v = xb[p];
            a0 += wr[0][p].x * u.x + wr[0][p].y * u.y + wr[0][p].z * u.z + wr[0][p].w * u.w;
            a1 += wr[1][p].x * u.x + wr[1][p].y * u.y + wr[1][p].z * u.z + wr[1][p].w * u.w;
            a2 += wr[2][p].x * u.x + wr[2][p].y * u.y + wr[2][p].z * u.z + wr[2][p].w * u.w;
            a3 += wr[3][p].x * u.x + wr[3][p].y * u.y + wr[3][p].z * u.z + wr[3][p].w * u.w;
            b0 += wr[0][p].x * v.x + wr[0][p].y * v.y + wr[0][p].z * v.z + wr[0][p].w * v.w;
            b1 += wr[1][p].x * v.x + wr[1][p].y * v.y + wr[1][p].z * v.z + wr[1][p].w * v.w;
            b2 += wr[2][p].x * v.x + wr[2][p].y * v.y + wr[2][p].z * v.z + wr[2][p].w * v.w;
            b3 += wr[3][p].x * v.x + wr[3][p].y * v.y + wr[3][p].z * v.z + wr[3][p].w * v.w;
        }

        // ---- folded reduction tree (bit-identical to full 32..1 butterfly) ----
        const float t0 = a0 + __shfl_xor(a0, 32, 64);
        const float t1 = a1 + __shfl_xor(a1, 32, 64);
        const float t2 = a2 + __shfl_xor(a2, 32, 64);
        const float t3 = a3 + __shfl_xor(a3, 32, 64);
        const float t4 = b0 + __shfl_xor(b0, 32, 64);
        const float t5 = b1 + __shfl_xor(b1, 32, 64);
        const float t6 = b2 + __shfl_xor(b2, 32, 64);
        const float t7 = b3 + __shfl_xor(b3, 32, 64);
        float w0 = hi32 ? t4 : t0;
        float w1 = hi32 ? t5 : t1;
        float w2 = hi32 ? t6 : t2;
        float w3 = hi32 ? t7 : t3;
        w0 += __shfl_xor(w0, 16, 64);
        w1 += __shfl_xor(w1, 16, 64);
        w2 += __shfl_xor(w2, 16, 64);
        w3 += __shfl_xor(w3, 16, 64);
        float u0 = hi16 ? w2 : w0;
        float u1 = hi16 ? w3 : w1;
        u0 += __shfl_xor(u0, 8, 64);
        u1 += __shfl_xor(u1, 8, 64);
        float z = hi8 ? u1 : u0;
        z += __shfl_xor(z, 4, 64);
        z += __shfl_xor(z, 2, 64);
        z += __shfl_xor(z, 1, 64);
        const float zp = __shfl_xor(z, 8, 64);   // partner row (r^1)

        const int r_id  = (hi8 ? 1 : 0) + (hi16 ? 2 : 0);
        const int s_idx = hi32 ? sb : sa;
        if ((lane & 7) == 0) {
            out[HOFF + (size_t)s_idx * FOUT2 + o0 + r_id] = z;
            if (!hi8) {   // even row: h = (logit_even >= logit_odd)
                out[(size_t)s_idx * (FOUT2 / 2) + (o0 >> 1) + (hi16 ? 1 : 0)]
                    = (z >= zp) ? 1.0f : 0.0f;
            }
        }
    }
}

extern "C" void kernel_launch(void* const* d_in, const int* in_sizes, int n_in,
                              void* d_out, int out_size, void* d_ws, size_t ws_size,
                              hipStream_t stream) {
    const float* x       = (const float*)d_in[0];
    const int*   task_id = (const int*)d_in[1];
    const float* W       = (const float*)d_in[2];
    float*       out     = (float*)d_out;

    dim3 grid(NW);
    dim3 block(64);
    hipLaunchKernelGGL(cond_linear_kernel, grid, block, 0, stream,
                       x, task_id, W, out);
}

// Round 13
// 31.162 us; speedup vs baseline: 1.4461x; 1.0920x over previous
//
#include <hip/hip_runtime.h>

#define FIN   1024
#define FOUT2 1024
#define NTASK 20
#define NRG   256                 // row-groups of 4 output rows
#define NW    (NTASK * NRG)       // 5120 single-wave blocks (NSLOT=1)
#define HOFF  (256 * 512)         // h output elements before logits

// Round-13 = round-9 (best, 29.4us) with ONE change: NSLOT 2 -> 1.
//  - Each wave handles ALL its task's samples (~6.4 vs ~3.2 pairs): the fixed
//    startup (16 W loads ~900cy + ballot) amortizes over 2x the FMA work.
//  - W L2/HBM traffic halves to the 80 MB minimum (read once per row-group).
//  - x traffic unchanged (a row-group covers all n samples either way).
// Everything else byte-for-byte round 9: ballot/rank list, pinned W, 1-pair
// prefetch, folded tree, XCD swizzle. Numerics bit-identical.
__global__ __launch_bounds__(64, 2)
void cond_linear_kernel(const float* __restrict__ x,
                        const int* __restrict__ task_id,
                        const float* __restrict__ W,
                        float* __restrict__ out) {
    __shared__ int sh_ord[64];

    const int lane = threadIdx.x;          // block == one wave
    const int bid  = blockIdx.x;
    const int orig = (bid & 7) * (NW / 8) + (bid >> 3);   // XCD-chunk swizzle
    const int t    = orig >> 8;            // 256 blocks per task
    const int rg   = orig & 255;           // row-group (4 rows)
    const int o0   = rg * 4;               // this wave's 4 output rows

    // ---- issue the 16 W loads FIRST (no barrier anywhere -> no drain) ----
    const float* Wt = W + (size_t)t * (FOUT2 * FIN);
    float4 wr[4][4];
    #pragma unroll
    for (int r = 0; r < 4; ++r) {
        const float4* wp = (const float4*)(Wt + (size_t)(o0 + r) * FIN);
        #pragma unroll
        for (int p = 0; p < 4; ++p)
            wr[r][p] = wp[p * 64 + lane];
    }

    // ---- barrier-free sample list: ballot + rank + per-wave LDS scatter ----
    const int4 ids = ((const int4*)task_id)[lane];        // samples 4l..4l+3
    const unsigned long long m0 = __ballot(ids.x == t);
    const unsigned long long m1 = __ballot(ids.y == t);
    const unsigned long long m2 = __ballot(ids.z == t);
    const unsigned long long m3 = __ballot(ids.w == t);
    const unsigned long long below = (1ull << lane) - 1ull;
    int rank = __popcll(m0 & below) + __popcll(m1 & below)
             + __popcll(m2 & below) + __popcll(m3 & below);
    if (ids.x == t) sh_ord[rank] = 4 * lane + 0;
    rank += (int)((m0 >> lane) & 1);
    if (ids.y == t) sh_ord[rank] = 4 * lane + 1;
    rank += (int)((m1 >> lane) & 1);
    if (ids.z == t) sh_ord[rank] = 4 * lane + 2;
    rank += (int)((m2 >> lane) & 1);
    if (ids.w == t) sh_ord[rank] = 4 * lane + 3;

    const int n = __popcll(m0) + __popcll(m1) + __popcll(m2) + __popcll(m3);
    const int i0 = 0;
    const int i1 = n;
    if (i0 >= i1) return;

    // ---- PIN W in VGPRs (no remat possible) ----
    #pragma unroll
    for (int r = 0; r < 4; ++r)
        #pragma unroll
        for (int p = 0; p < 4; ++p)
            asm volatile("" : "+v"(wr[r][p].x), "+v"(wr[r][p].y),
                              "+v"(wr[r][p].z), "+v"(wr[r][p].w));

    // lane identity bits for the folded tree
    const bool hi32 = (lane & 32) != 0;
    const bool hi16 = (lane & 16) != 0;
    const bool hi8  = (lane & 8)  != 0;

    // ---- preload first sample pair ----
    int sa = sh_ord[i0];
    int sb = sh_ord[(i0 + 1 < i1) ? i0 + 1 : i1 - 1];
    float4 xa[4], xb[4];
    #pragma unroll
    for (int p = 0; p < 4; ++p)
        xa[p] = ((const float4*)(x + (size_t)sa * FIN))[p * 64 + lane];
    #pragma unroll
    for (int p = 0; p < 4; ++p)
        xb[p] = ((const float4*)(x + (size_t)sb * FIN))[p * 64 + lane];

    for (int i = i0; i < i1; i += 2) {
        // prefetch next pair (clamped; tail duplicates are benign)
        const int ina = (i + 2 < i1) ? i + 2 : i1 - 1;
        const int inb = (i + 3 < i1) ? i + 3 : i1 - 1;
        const int na_s = sh_ord[ina];
        const int nb_s = sh_ord[inb];
        float4 na[4], nb[4];
        #pragma unroll
        for (int p = 0; p < 4; ++p)
            na[p] = ((const float4*)(x + (size_t)na_s * FIN))[p * 64 + lane];
        #pragma unroll
        for (int p = 0; p < 4; ++p)
            nb[p] = ((const float4*)(x + (size_t)nb_s * FIN))[p * 64 + lane];

        float a0 = 0.f, a1 = 0.f, a2 = 0.f, a3 = 0.f;
        float b0 = 0.f, b1 = 0.f, b2 = 0.f, b3 = 0.f;
        #pragma unroll
        for (int p = 0; p < 4; ++p) {
            const float4 u = xa[p];
            const float4 v = xb[p];
            a0 += wr[0][p].x * u.x + wr[0][p].y * u.y + wr[0][p].z * u.z + wr[0][p].w * u.w;
            a1 += wr[1][p].x * u.x + wr[1][p].y * u.y + wr[1][p].z * u.z + wr[1][p].w * u.w;
            a2 += wr[2][p].x * u.x + wr[2][p].y * u.y + wr[2][p].z * u.z + wr[2][p].w * u.w;
            a3 += wr[3][p].x * u.x + wr[3][p].y * u.y + wr[3][p].z * u.z + wr[3][p].w * u.w;
            b0 += wr[0][p].x * v.x + wr[0][p].y * v.y + wr[0][p].z * v.z + wr[0][p].w * v.w;
            b1 += wr[1][p].x * v.x + wr[1][p].y * v.y + wr[1][p].z * v.z + wr[1][p].w * v.w;
            b2 += wr[2][p].x * v.x + wr[2][p].y * v.y + wr[2][p].z * v.z + wr[2][p].w * v.w;
            b3 += wr[3][p].x * v.x + wr[3][p].y * v.y + wr[3][p].z * v.z + wr[3][p].w * v.w;
        }

        // ---- folded reduction tree (bit-identical to full 32..1 butterfly) ----
        const float t0 = a0 + __shfl_xor(a0, 32, 64);
        const float t1 = a1 + __shfl_xor(a1, 32, 64);
        const float t2 = a2 + __shfl_xor(a2, 32, 64);
        const float t3 = a3 + __shfl_xor(a3, 32, 64);
        const float t4 = b0 + __shfl_xor(b0, 32, 64);
        const float t5 = b1 + __shfl_xor(b1, 32, 64);
        const float t6 = b2 + __shfl_xor(b2, 32, 64);
        const float t7 = b3 + __shfl_xor(b3, 32, 64);
        float w0 = hi32 ? t4 : t0;
        float w1 = hi32 ? t5 : t1;
        float w2 = hi32 ? t6 : t2;
        float w3 = hi32 ? t7 : t3;
        w0 += __shfl_xor(w0, 16, 64);
        w1 += __shfl_xor(w1, 16, 64);
        w2 += __shfl_xor(w2, 16, 64);
        w3 += __shfl_xor(w3, 16, 64);
        float u0 = hi16 ? w2 : w0;
        float u1 = hi16 ? w3 : w1;
        u0 += __shfl_xor(u0, 8, 64);
        u1 += __shfl_xor(u1, 8, 64);
        float z = hi8 ? u1 : u0;
        z += __shfl_xor(z, 4, 64);
        z += __shfl_xor(z, 2, 64);
        z += __shfl_xor(z, 1, 64);
        const float zp = __shfl_xor(z, 8, 64);   // partner row (r^1)

        const int r_id  = (hi8 ? 1 : 0) + (hi16 ? 2 : 0);
        const int s_idx = hi32 ? sb : sa;
        if ((lane & 7) == 0) {
            out[HOFF + (size_t)s_idx * FOUT2 + o0 + r_id] = z;
            if (!hi8) {   // even row: h = (logit_even >= logit_odd)
                out[(size_t)s_idx * (FOUT2 / 2) + (o0 >> 1) + (hi16 ? 1 : 0)]
                    = (z >= zp) ? 1.0f : 0.0f;
            }
        }

        sa = na_s; sb = nb_s;
        #pragma unroll
        for (int p = 0; p < 4; ++p) { xa[p] = na[p]; xb[p] = nb[p]; }
    }
}

extern "C" void kernel_launch(void* const* d_in, const int* in_sizes, int n_in,
                              void* d_out, int out_size, void* d_ws, size_t ws_size,
                              hipStream_t stream) {
    const float* x       = (const float*)d_in[0];
    const int*   task_id = (const int*)d_in[1];
    const float* W       = (const float*)d_in[2];
    float*       out     = (float*)d_out;

    dim3 grid(NW);
    dim3 block(64);
    hipLaunchKernelGGL(cond_linear_kernel, grid, block, 0, stream,
                       x, task_id, W, out);
}